// Round 3
// baseline (879.936 us; speedup 1.0000x reference)
//
#include <hip/hip_runtime.h>

#define T_TOK 4096
#define H_DIM 1024
#define I_DIM 4096
#define E_NUM 8

typedef __attribute__((ext_vector_type(8))) short short8;
typedef __attribute__((ext_vector_type(4))) float floatx4;
typedef __attribute__((ext_vector_type(16))) float floatx16;

__device__ __forceinline__ unsigned short f2bf(float f) {
    union { float f; unsigned u; } v; v.f = f;
    unsigned r = v.u + 0x7fffu + ((v.u >> 16) & 1u);  // round-to-nearest-even
    return (unsigned short)(r >> 16);
}

__device__ __forceinline__ void gl_lds16(const unsigned short* g, unsigned short* l) {
    __builtin_amdgcn_global_load_lds((const __attribute__((address_space(1))) void*)g,
                                     (__attribute__((address_space(3))) void*)l, 16, 0, 0);
}

// ---------------- router: logits (fp32), top-2 softmax, expert histogram ----------------
__global__ __launch_bounds__(256) void router_kernel(
    const float* __restrict__ hidden, const float* __restrict__ gate,
    float* __restrict__ logits, int* __restrict__ ws_i,
    int* __restrict__ e0a, int* __restrict__ e1a,
    float* __restrict__ p0a, float* __restrict__ p1a)
{
    int lane = threadIdx.x & 63;
    int t = blockIdx.x * 4 + (threadIdx.x >> 6);
    const float* hrow = hidden + (size_t)t * H_DIM;
    float acc[E_NUM];
#pragma unroll
    for (int e = 0; e < E_NUM; e++) acc[e] = 0.f;
    for (int h = lane; h < H_DIM; h += 64) {
        float x = hrow[h];
        const float4* g = (const float4*)(gate + (size_t)h * E_NUM);
        float4 g0 = g[0], g1 = g[1];
        acc[0] += x * g0.x; acc[1] += x * g0.y; acc[2] += x * g0.z; acc[3] += x * g0.w;
        acc[4] += x * g1.x; acc[5] += x * g1.y; acc[6] += x * g1.z; acc[7] += x * g1.w;
    }
#pragma unroll
    for (int e = 0; e < E_NUM; e++) {
#pragma unroll
        for (int off = 32; off > 0; off >>= 1)
            acc[e] += __shfl_xor(acc[e], off, 64);
    }
    if (lane == 0) {
#pragma unroll
        for (int e = 0; e < E_NUM; e++) logits[(size_t)t * E_NUM + e] = acc[e];
        int e0 = 0;
#pragma unroll
        for (int e = 1; e < E_NUM; e++) if (acc[e] > acc[e0]) e0 = e;   // strict > == first-index tie-break
        int e1 = (e0 == 0) ? 1 : 0;
#pragma unroll
        for (int e = 0; e < E_NUM; e++) if (e != e0 && acc[e] > acc[e1]) e1 = e;
        float z = __expf(acc[e1] - acc[e0]);
        float p0 = 1.f / (1.f + z);
        e0a[t] = e0; e1a[t] = e1; p0a[t] = p0; p1a[t] = 1.f - p0;
        atomicAdd(ws_i + e0, 1);
        atomicAdd(ws_i + e1, 1);
    }
}

// ---------------- prefix sum over 8 experts ----------------
__global__ void prefix_kernel(int* ws_i) {
    if (threadIdx.x == 0) {
        int run = 0;
#pragma unroll
        for (int e = 0; e < E_NUM; e++) {
            ws_i[8 + e] = run;    // base
            ws_i[16 + e] = run;   // cursor
            run += ws_i[e];
        }
    }
}

// ---------------- token->slot assignment + hidden fp32->bf16 ----------------
__global__ __launch_bounds__(256) void assign_cvt_kernel(
    const float* __restrict__ hidden, int* __restrict__ ws_i,
    const int* __restrict__ e0a, const int* __restrict__ e1a,
    const float* __restrict__ p0a, const float* __restrict__ p1a,
    int* __restrict__ token_id, float* __restrict__ tok_w,
    unsigned short* __restrict__ hbf)
{
    int tid = blockIdx.x * 256 + threadIdx.x;
    if (tid < T_TOK) {
        int s0 = atomicAdd(ws_i + 16 + e0a[tid], 1);
        token_id[s0] = tid; tok_w[s0] = p0a[tid];
        int s1 = atomicAdd(ws_i + 16 + e1a[tid], 1);
        token_id[s1] = tid; tok_w[s1] = p1a[tid];
    }
    size_t off = (size_t)tid * 8;
    const float4* src = (const float4*)(hidden + off);
    float4 a = src[0], b = src[1];
    short8 pk;
    pk[0] = (short)f2bf(a.x); pk[1] = (short)f2bf(a.y);
    pk[2] = (short)f2bf(a.z); pk[3] = (short)f2bf(a.w);
    pk[4] = (short)f2bf(b.x); pk[5] = (short)f2bf(b.y);
    pk[6] = (short)f2bf(b.z); pk[7] = (short)f2bf(b.w);
    *(short8*)(hbf + off) = pk;
}

// ---------------- fused transpose + fp32->bf16 for w1, w3, w2 (one launch) ----------------
// blockIdx.x in [0, 3*8192): which = z>>13, e = (z&8191)>>10, tile = z&1023
__global__ __launch_bounds__(256) void cvt_all_kernel(
    const float* __restrict__ w1, const float* __restrict__ w3, const float* __restrict__ w2,
    unsigned short* __restrict__ w1t, unsigned short* __restrict__ w3t, unsigned short* __restrict__ w2t)
{
    __shared__ float tile[64][65];
    int z = blockIdx.x;
    int which = z >> 13;
    int rem = z & 8191;
    int e = rem >> 10;
    int t2 = rem & 1023;
    const float* src; unsigned short* dst; int R, C, cx, ry;
    if (which == 0)      { src = w1; dst = w1t; R = H_DIM; C = I_DIM; cx = t2 & 63; ry = t2 >> 6; }
    else if (which == 1) { src = w3; dst = w3t; R = H_DIM; C = I_DIM; cx = t2 & 63; ry = t2 >> 6; }
    else                 { src = w2; dst = w2t; R = I_DIM; C = H_DIM; cx = t2 & 15; ry = t2 >> 4; }
    src += (size_t)e * R * C;
    dst += (size_t)e * R * C;
    int c0 = cx * 64, r0 = ry * 64;
    int t = threadIdx.x;
    int cc = (t & 15) * 4;
    int rr = t >> 4;
#pragma unroll
    for (int p = 0; p < 4; p++) {
        int r = rr + p * 16;
        float4 v = *(const float4*)(src + (size_t)(r0 + r) * C + c0 + cc);
        tile[r][cc] = v.x; tile[r][cc + 1] = v.y; tile[r][cc + 2] = v.z; tile[r][cc + 3] = v.w;
    }
    __syncthreads();
    int c = t >> 3;
    int rg = (t & 7) * 8;
#pragma unroll
    for (int p = 0; p < 2; p++) {
        int cc2 = c + p * 32;
        short8 pk;
#pragma unroll
        for (int j = 0; j < 8; j++) pk[j] = (short)f2bf(tile[rg + j][cc2]);
        *(short8*)(dst + (size_t)(c0 + cc2) * R + r0 + rg) = pk;
    }
}

// ================= GEMMs: 32x32x16 MFMA, BK=64, XOR-swizzled LDS via source chunk select =====
// LDS row = 64 bf16 = 128 B (8 chunks of 16 B). Logical chunk c of row r stored at physical
// chunk c ^ (r & 7). gl_lds dest is wave-uniform + lane*16, so the swizzle is applied by
// redirecting WHICH global chunk each lane fetches. All fragment reads apply the same map.

// fused up-proj: act = silu(A@w1) * (A@w3); BM=128, BN=64, BK=64; 4 waves, wave tile 64x32 per matrix
__global__ __launch_bounds__(256) void up_kernel(
    const unsigned short* __restrict__ w1t,  // [e][I][H] bf16
    const unsigned short* __restrict__ w3t,
    const unsigned short* __restrict__ hbf,  // [T][H] bf16
    const int* __restrict__ ws_i, const int* __restrict__ token_id,
    unsigned short* __restrict__ act)        // [2T][I] bf16 (slot rows)
{
    int e = blockIdx.z;
    int n_e = ws_i[e];
    int m0 = blockIdx.y * 128;
    if (m0 >= n_e) return;
    int base = ws_i[8 + e];
    int n0 = blockIdx.x * 64;

    __shared__ __align__(16) unsigned short sA[128 * 64];   // 16 KB
    __shared__ __align__(16) unsigned short sB1[64 * 64];   // 8 KB
    __shared__ __align__(16) unsigned short sB3[64 * 64];   // 8 KB

    int tid = threadIdx.x;
    int lane = tid & 63;
    int wv = tid >> 6;
    int wm = (wv & 1) * 64;
    int wn = (wv >> 1) * 32;
    int nl = lane & 31;
    int kh = lane >> 5;

    // staging: lane -> (row-in-8-group = lane>>3, phys chunk = lane&7), logical chunk swizzled
    int rsub = lane >> 3;
    int csw = (lane & 7) ^ rsub;             // logical chunk this lane must fetch
    const unsigned short* ga[4];
#pragma unroll
    for (int j = 0; j < 4; j++) {
        int rs = wv * 32 + j * 8 + rsub;     // A row within block tile
        int r = m0 + rs; if (r > n_e - 1) r = n_e - 1;
        ga[j] = hbf + (size_t)token_id[base + r] * H_DIM + csw * 8;
    }
    const unsigned short* wb1 = w1t + (size_t)e * I_DIM * H_DIM;
    const unsigned short* wb3 = w3t + (size_t)e * I_DIM * H_DIM;
    const unsigned short* gb1[2];
    const unsigned short* gb3[2];
#pragma unroll
    for (int j = 0; j < 2; j++) {
        int rs = wv * 16 + j * 8 + rsub;
        gb1[j] = wb1 + (size_t)(n0 + rs) * H_DIM + csw * 8;
        gb3[j] = wb3 + (size_t)(n0 + rs) * H_DIM + csw * 8;
    }
    unsigned short* lA[4];
    unsigned short* lB1[2];
    unsigned short* lB3[2];
#pragma unroll
    for (int j = 0; j < 4; j++) lA[j] = sA + (wv * 32 + j * 8) * 64;
#pragma unroll
    for (int j = 0; j < 2; j++) {
        lB1[j] = sB1 + (wv * 16 + j * 8) * 64;
        lB3[j] = sB3 + (wv * 16 + j * 8) * 64;
    }

    floatx16 acc1[2], acc3[2];
#pragma unroll
    for (int i = 0; i < 2; i++) {
#pragma unroll
        for (int r = 0; r < 16; r++) { acc1[i][r] = 0.f; acc3[i][r] = 0.f; }
    }

    int p7 = nl & 7;  // row&7 for all fragment rows this lane touches
    for (int k0 = 0; k0 < H_DIM; k0 += 64) {
#pragma unroll
        for (int j = 0; j < 4; j++) gl_lds16(ga[j] + k0, lA[j]);
#pragma unroll
        for (int j = 0; j < 2; j++) {
            gl_lds16(gb1[j] + k0, lB1[j]);
            gl_lds16(gb3[j] + k0, lB3[j]);
        }
        __syncthreads();
#pragma unroll
        for (int h = 0; h < 4; h++) {
            int ch = h * 2 + kh;                 // logical chunk for this MFMA k-half
            int pc = (ch ^ p7) * 8;              // physical elem offset in row
            short8 a0 = *(const short8*)(sA + (wm + nl) * 64 + pc);
            short8 a1 = *(const short8*)(sA + (wm + 32 + nl) * 64 + pc);
            short8 b1 = *(const short8*)(sB1 + (wn + nl) * 64 + pc);
            short8 b3 = *(const short8*)(sB3 + (wn + nl) * 64 + pc);
            acc1[0] = __builtin_amdgcn_mfma_f32_32x32x16_bf16(a0, b1, acc1[0], 0, 0, 0);
            acc3[0] = __builtin_amdgcn_mfma_f32_32x32x16_bf16(a0, b3, acc3[0], 0, 0, 0);
            acc1[1] = __builtin_amdgcn_mfma_f32_32x32x16_bf16(a1, b1, acc1[1], 0, 0, 0);
            acc3[1] = __builtin_amdgcn_mfma_f32_32x32x16_bf16(a1, b3, acc3[1], 0, 0, 0);
        }
        __syncthreads();
    }

    // C/D layout (verified): col = lane&31, row = (reg&3) + 8*(reg>>2) + 4*(lane>>5)
#pragma unroll
    for (int mi = 0; mi < 2; mi++) {
#pragma unroll
        for (int r = 0; r < 16; r++) {
            int mrel = (r & 3) + 4 * kh + 8 * (r >> 2);
            int gm = m0 + wm + mi * 32 + mrel;
            if (gm < n_e) {
                float x = acc1[mi][r], y = acc3[mi][r];
                float s = x / (1.f + __expf(-x)) * y;
                act[(size_t)(base + gm) * I_DIM + n0 + wn + nl] = f2bf(s);
            }
        }
    }
}

// down-proj: out[t] += w_t * (act @ w2); BM=128, BN=128, BK=64; 4 waves, wave tile 64x64
__global__ __launch_bounds__(256) void down_kernel(
    const unsigned short* __restrict__ w2t,  // [e][H][I] bf16
    const unsigned short* __restrict__ act,
    const int* __restrict__ ws_i, const int* __restrict__ token_id,
    const float* __restrict__ tok_w,
    float* __restrict__ out)
{
    int e = blockIdx.z;
    int n_e = ws_i[e];
    int m0 = blockIdx.y * 128;
    if (m0 >= n_e) return;
    int base = ws_i[8 + e];
    int n0 = blockIdx.x * 128;

    __shared__ __align__(16) unsigned short sA[128 * 64];   // 16 KB
    __shared__ __align__(16) unsigned short sB[128 * 64];   // 16 KB

    int tid = threadIdx.x;
    int lane = tid & 63;
    int wv = tid >> 6;
    int wm = (wv >> 1) * 64;
    int wn = (wv & 1) * 64;
    int nl = lane & 31;
    int kh = lane >> 5;

    int rsub = lane >> 3;
    int csw = (lane & 7) ^ rsub;
    const unsigned short* ga[4];
    const unsigned short* gb[4];
#pragma unroll
    for (int j = 0; j < 4; j++) {
        int rs = wv * 32 + j * 8 + rsub;
        int r = m0 + rs; if (r > n_e - 1) r = n_e - 1;
        ga[j] = act + (size_t)(base + r) * I_DIM + csw * 8;
        gb[j] = w2t + (size_t)e * H_DIM * I_DIM + (size_t)(n0 + rs) * I_DIM + csw * 8;
    }
    unsigned short* lA[4];
    unsigned short* lB[4];
#pragma unroll
    for (int j = 0; j < 4; j++) {
        lA[j] = sA + (wv * 32 + j * 8) * 64;
        lB[j] = sB + (wv * 32 + j * 8) * 64;
    }

    floatx16 acc[4];
#pragma unroll
    for (int i = 0; i < 4; i++) {
#pragma unroll
        for (int r = 0; r < 16; r++) acc[i][r] = 0.f;
    }

    int p7 = nl & 7;
    for (int k0 = 0; k0 < I_DIM; k0 += 64) {
#pragma unroll
        for (int j = 0; j < 4; j++) gl_lds16(ga[j] + k0, lA[j]);
#pragma unroll
        for (int j = 0; j < 4; j++) gl_lds16(gb[j] + k0, lB[j]);
        __syncthreads();
#pragma unroll
        for (int h = 0; h < 4; h++) {
            int ch = h * 2 + kh;
            int pc = (ch ^ p7) * 8;
            short8 a0 = *(const short8*)(sA + (wm + nl) * 64 + pc);
            short8 a1 = *(const short8*)(sA + (wm + 32 + nl) * 64 + pc);
            short8 b0 = *(const short8*)(sB + (wn + nl) * 64 + pc);
            short8 b1 = *(const short8*)(sB + (wn + 32 + nl) * 64 + pc);
            acc[0] = __builtin_amdgcn_mfma_f32_32x32x16_bf16(a0, b0, acc[0], 0, 0, 0);
            acc[1] = __builtin_amdgcn_mfma_f32_32x32x16_bf16(a0, b1, acc[1], 0, 0, 0);
            acc[2] = __builtin_amdgcn_mfma_f32_32x32x16_bf16(a1, b0, acc[2], 0, 0, 0);
            acc[3] = __builtin_amdgcn_mfma_f32_32x32x16_bf16(a1, b1, acc[3], 0, 0, 0);
        }
        __syncthreads();
    }

#pragma unroll
    for (int mi = 0; mi < 2; mi++) {
#pragma unroll
        for (int r = 0; r < 16; r++) {
            int mrel = (r & 3) + 4 * kh + 8 * (r >> 2);
            int gm = m0 + wm + mi * 32 + mrel;
            if (gm < n_e) {
                int gs = base + gm;
                int t = token_id[gs];
                float wgt = tok_w[gs];
                float* orow = out + (size_t)t * H_DIM + n0 + wn;
#pragma unroll
                for (int ni = 0; ni < 2; ni++)
                    atomicAdd(orow + ni * 32 + nl, wgt * acc[mi * 2 + ni][r]);
            }
        }
    }
}

extern "C" void kernel_launch(void* const* d_in, const int* in_sizes, int n_in,
                              void* d_out, int out_size, void* d_ws, size_t ws_size,
                              hipStream_t stream) {
    const float* hidden = (const float*)d_in[0];
    const float* gate   = (const float*)d_in[1];
    const float* w1     = (const float*)d_in[2];
    const float* w3     = (const float*)d_in[3];
    const float* w2     = (const float*)d_in[4];
    float* out_final  = (float*)d_out;
    float* out_logits = out_final + (size_t)T_TOK * H_DIM;

    // workspace layout (~337 MB; round-2 run confirmed ws_size suffices)
    char* wsb = (char*)d_ws;
    int*   ws_i     = (int*)wsb;                              // counts[8], base[8], cursor[8]
    int*   e0a      = (int*)(wsb + 256);                      // [T]
    int*   e1a      = e0a + T_TOK;
    float* p0a      = (float*)(e1a + T_TOK);
    float* p1a      = p0a + T_TOK;
    int*   token_id = (int*)(p1a + T_TOK);                    // [2T]
    float* tok_w    = (float*)(token_id + 2 * T_TOK);         // [2T]
    unsigned short* hbf = (unsigned short*)(tok_w + 2 * T_TOK);   // [T*H] bf16
    unsigned short* act = hbf + (size_t)T_TOK * H_DIM;            // [2T*I] bf16
    unsigned short* w1t = act + (size_t)2 * T_TOK * I_DIM;        // [E][I][H] bf16
    unsigned short* w3t = w1t + (size_t)E_NUM * I_DIM * H_DIM;
    unsigned short* w2t = w3t + (size_t)E_NUM * I_DIM * H_DIM;    // [E][H][I] bf16

    hipMemsetAsync(d_out, 0, (size_t)T_TOK * H_DIM * sizeof(float), stream);
    hipMemsetAsync(d_ws, 0, 256, stream);

    router_kernel<<<T_TOK / 4, 256, 0, stream>>>(hidden, gate, out_logits, ws_i, e0a, e1a, p0a, p1a);
    prefix_kernel<<<1, 64, 0, stream>>>(ws_i);
    assign_cvt_kernel<<<(T_TOK * H_DIM / 8) / 256, 256, 0, stream>>>(
        hidden, ws_i, e0a, e1a, p0a, p1a, token_id, tok_w, hbf);
    cvt_all_kernel<<<3 * E_NUM * 1024, 256, 0, stream>>>(w1, w3, w2, w1t, w3t, w2t);
    up_kernel<<<dim3(I_DIM / 64, T_TOK / 128, E_NUM), 256, 0, stream>>>(
        w1t, w3t, hbf, ws_i, token_id, act);
    down_kernel<<<dim3(H_DIM / 128, T_TOK / 128, E_NUM), 256, 0, stream>>>(
        w2t, act, ws_i, token_id, tok_w, out_final);
}